// Round 1
// baseline (769.124 us; speedup 1.0000x reference)
//
#include <hip/hip_runtime.h>
#include <math.h>

#define NODES 50000
#define NEDGES 800000
#define TOT_E (NEDGES + NODES)

static __device__ __forceinline__ float lrelu(float z) {
  return z > 0.f ? z : 0.2f * z;
}

// ---------------- CSR build ----------------
__global__ void k_hist(const int* __restrict__ dst, int* __restrict__ counts) {
  int stride = gridDim.x * blockDim.x;
  for (int i = blockIdx.x * blockDim.x + threadIdx.x; i < TOT_E; i += stride) {
    int d = (i < NEDGES) ? dst[i] : (i - NEDGES);
    atomicAdd(&counts[d], 1);
  }
}

__global__ void k_scan(const int* __restrict__ counts, int* __restrict__ offs) {
  __shared__ int part[1024];
  const int n = NODES;
  int tid = threadIdx.x;
  int chunk = (n + 1023) / 1024;
  int b = tid * chunk;
  int e = min(b + chunk, n);
  int sum = 0;
  for (int i = b; i < e; ++i) sum += counts[i];
  part[tid] = sum;
  __syncthreads();
  for (int off = 1; off < 1024; off <<= 1) {
    int v = (tid >= off) ? part[tid - off] : 0;
    __syncthreads();
    part[tid] += v;
    __syncthreads();
  }
  int base = (tid == 0) ? 0 : part[tid - 1];
  for (int i = b; i < e; ++i) { offs[i] = base; base += counts[i]; }
  if (tid == 1023) offs[n] = base;
}

__global__ void k_copy_cursor(const int* __restrict__ offs, int* __restrict__ cur) {
  int i = blockIdx.x * blockDim.x + threadIdx.x;
  if (i < NODES) cur[i] = offs[i];
}

__global__ void k_scatter(const int* __restrict__ src, const int* __restrict__ dst,
                          int* __restrict__ cur, int* __restrict__ ssrc) {
  int stride = gridDim.x * blockDim.x;
  for (int i = blockIdx.x * blockDim.x + threadIdx.x; i < TOT_E; i += stride) {
    int s, d;
    if (i < NEDGES) { s = src[i]; d = dst[i]; } else { s = i - NEDGES; d = s; }
    int pos = atomicAdd(&cur[d], 1);
    ssrc[pos] = s;
  }
}

// ---------------- f32 tiled GEMM: C[M,N] = A[M,K] * B[K,N] ----------------
#define BM 64
#define BN 64
#define BK 16

__global__ __launch_bounds__(256) void k_gemm(const float* __restrict__ A,
    const float* __restrict__ B, float* __restrict__ C, int M, int N, int K) {
  __shared__ float As[BK][BM + 4];  // transposed: As[k][m]
  __shared__ float Bs[BK][BN + 4];
  int tid = threadIdx.x;
  int rowBase = blockIdx.x * BM;
  int colBase = blockIdx.y * BN;
  int tx = tid & 15, ty = tid >> 4;
  float acc[4][4] = {{0.f,0.f,0.f,0.f},{0.f,0.f,0.f,0.f},{0.f,0.f,0.f,0.f},{0.f,0.f,0.f,0.f}};
  for (int k0 = 0; k0 < K; k0 += BK) {
    {
      int r = tid >> 2, c4 = (tid & 3) * 4;
      int grow = rowBase + r;
      float4 v = make_float4(0.f, 0.f, 0.f, 0.f);
      if (grow < M) v = *(const float4*)&A[(size_t)grow * K + k0 + c4];
      As[c4 + 0][r] = v.x; As[c4 + 1][r] = v.y; As[c4 + 2][r] = v.z; As[c4 + 3][r] = v.w;
    }
    {
      int r = tid >> 4, c4 = (tid & 15) * 4;
      int gcol = colBase + c4;
      const float* brow = &B[(size_t)(k0 + r) * N];
      float4 v = make_float4(0.f, 0.f, 0.f, 0.f);
      if (gcol + 3 < N) {
        v = *(const float4*)&brow[gcol];
      } else {
        if (gcol + 0 < N) v.x = brow[gcol + 0];
        if (gcol + 1 < N) v.y = brow[gcol + 1];
        if (gcol + 2 < N) v.z = brow[gcol + 2];
      }
      *(float4*)&Bs[r][c4] = v;
    }
    __syncthreads();
#pragma unroll
    for (int k = 0; k < BK; ++k) {
      float4 a = *(const float4*)&As[k][ty * 4];
      float4 b = *(const float4*)&Bs[k][tx * 4];
      acc[0][0] += a.x * b.x; acc[0][1] += a.x * b.y; acc[0][2] += a.x * b.z; acc[0][3] += a.x * b.w;
      acc[1][0] += a.y * b.x; acc[1][1] += a.y * b.y; acc[1][2] += a.y * b.z; acc[1][3] += a.y * b.w;
      acc[2][0] += a.z * b.x; acc[2][1] += a.z * b.y; acc[2][2] += a.z * b.z; acc[2][3] += a.z * b.w;
      acc[3][0] += a.w * b.x; acc[3][1] += a.w * b.y; acc[3][2] += a.w * b.z; acc[3][3] += a.w * b.w;
    }
    __syncthreads();
  }
#pragma unroll
  for (int i = 0; i < 4; ++i) {
    int row = rowBase + ty * 4 + i;
    if (row >= M) continue;
#pragma unroll
    for (int j = 0; j < 4; ++j) {
      int col = colBase + tx * 4 + j;
      if (col < N) C[(size_t)row * N + col] = acc[i][j];
    }
  }
}

// ---------------- attention logits per node ----------------
// H=4, C=64: wave per node, lane owns 4 channels (float4); heads are 16-lane groups.
__global__ __launch_bounds__(256) void k_alog4(const float* __restrict__ h,
    const float* __restrict__ a_s, const float* __restrict__ a_d,
    float* __restrict__ al_s, float* __restrict__ al_d) {
  int wid = (blockIdx.x * blockDim.x + threadIdx.x) >> 6;
  if (wid >= NODES) return;
  int lane = threadIdx.x & 63;
  float4 hv = *(const float4*)&h[(size_t)wid * 256 + lane * 4];
  float4 sv = *(const float4*)&a_s[lane * 4];
  float4 dv = *(const float4*)&a_d[lane * 4];
  float ps = hv.x * sv.x + hv.y * sv.y + hv.z * sv.z + hv.w * sv.w;
  float pd = hv.x * dv.x + hv.y * dv.y + hv.z * dv.z + hv.w * dv.w;
#pragma unroll
  for (int off = 1; off <= 8; off <<= 1) {
    ps += __shfl_xor(ps, off);
    pd += __shfl_xor(pd, off);
  }
  if ((lane & 15) == 0) {
    al_s[wid * 4 + (lane >> 4)] = ps;
    al_d[wid * 4 + (lane >> 4)] = pd;
  }
}

// H=1, C=40
__global__ __launch_bounds__(256) void k_alog1(const float* __restrict__ h,
    const float* __restrict__ a_s, const float* __restrict__ a_d,
    float* __restrict__ al_s, float* __restrict__ al_d) {
  int wid = (blockIdx.x * blockDim.x + threadIdx.x) >> 6;
  if (wid >= NODES) return;
  int lane = threadIdx.x & 63;
  float ps = 0.f, pd = 0.f;
  if (lane < 40) {
    float hv = h[(size_t)wid * 40 + lane];
    ps = hv * a_s[lane];
    pd = hv * a_d[lane];
  }
#pragma unroll
  for (int off = 1; off <= 32; off <<= 1) {
    ps += __shfl_xor(ps, off);
    pd += __shfl_xor(pd, off);
  }
  if (lane == 0) { al_s[wid] = ps; al_d[wid] = pd; }
}

// ---------------- aggregation: wave per dst node ----------------
// layers 0/1: H=4, C=64, fused bias + ELU
__global__ __launch_bounds__(256) void k_agg4(const float* __restrict__ h,
    const float* __restrict__ al_s, const float* __restrict__ al_d,
    const int* __restrict__ offs, const int* __restrict__ ssrc,
    const float* __restrict__ bias, float* __restrict__ out) {
  int wid = (blockIdx.x * blockDim.x + threadIdx.x) >> 6;
  if (wid >= NODES) return;
  int lane = threadIdx.x & 63;
  int beg = offs[wid], end = offs[wid + 1];
  int h1 = lane >> 4;   // head (0..3): same grouping for phase 1 and 2
  int es = lane & 15;   // edge slot in phase 1
  float ald = al_d[wid * 4 + h1];

  // phase 1: online softmax stats per head
  float m = -1e30f, s = 0.f;
  for (int i = beg + es; i < end; i += 16) {
    int sv = ssrc[i];
    float z = lrelu(al_s[sv * 4 + h1] + ald);
    if (z > m) { s = s * __expf(m - z) + 1.f; m = z; }
    else s += __expf(z - m);
  }
#pragma unroll
  for (int off = 1; off <= 8; off <<= 1) {
    float mo = __shfl_xor(m, off), so = __shfl_xor(s, off);
    float mn = fmaxf(m, mo);
    s = s * __expf(m - mn) + so * __expf(mo - mn);
    m = mn;
  }
  float inv = 1.f / s;

  // phase 2: weighted gather-accumulate; lane owns channels [lane*4, lane*4+4)
  float4 acc = make_float4(0.f, 0.f, 0.f, 0.f);
  int cbase = lane * 4;
  for (int i = beg; i < end; ++i) {
    int sv = ssrc[i];
    float z = lrelu(al_s[sv * 4 + h1] + ald);
    float alpha = __expf(z - m) * inv;
    float4 hv = *(const float4*)&h[(size_t)sv * 256 + cbase];
    acc.x += alpha * hv.x; acc.y += alpha * hv.y;
    acc.z += alpha * hv.z; acc.w += alpha * hv.w;
  }
  float4 bv = *(const float4*)&bias[cbase];
  float vx = acc.x + bv.x, vy = acc.y + bv.y, vz = acc.z + bv.z, vw = acc.w + bv.w;
  float4 o;
  o.x = vx > 0.f ? vx : __expf(vx) - 1.f;
  o.y = vy > 0.f ? vy : __expf(vy) - 1.f;
  o.z = vz > 0.f ? vz : __expf(vz) - 1.f;
  o.w = vw > 0.f ? vw : __expf(vw) - 1.f;
  *(float4*)&out[(size_t)wid * 256 + cbase] = o;
}

// layer 2: H=1, C=40, fused bias + log_softmax, writes final output
__global__ __launch_bounds__(256) void k_agg1(const float* __restrict__ h,
    const float* __restrict__ al_s, const float* __restrict__ al_d,
    const int* __restrict__ offs, const int* __restrict__ ssrc,
    const float* __restrict__ bias, float* __restrict__ out) {
  int wid = (blockIdx.x * blockDim.x + threadIdx.x) >> 6;
  if (wid >= NODES) return;
  int lane = threadIdx.x & 63;
  int beg = offs[wid], end = offs[wid + 1];
  float ald = al_d[wid];

  float m = -1e30f, s = 0.f;
  for (int i = beg + lane; i < end; i += 64) {
    float z = lrelu(al_s[ssrc[i]] + ald);
    if (z > m) { s = s * __expf(m - z) + 1.f; m = z; }
    else s += __expf(z - m);
  }
#pragma unroll
  for (int off = 1; off <= 32; off <<= 1) {
    float mo = __shfl_xor(m, off), so = __shfl_xor(s, off);
    float mn = fmaxf(m, mo);
    s = s * __expf(m - mn) + so * __expf(mo - mn);
    m = mn;
  }
  float inv = 1.f / s;

  float acc = 0.f;
  bool act = lane < 40;
  for (int i = beg; i < end; ++i) {
    int sv = ssrc[i];
    float z = lrelu(al_s[sv] + ald);
    float alpha = __expf(z - m) * inv;
    if (act) acc += alpha * h[(size_t)sv * 40 + lane];
  }
  float v = act ? acc + bias[lane] : -1e30f;
  float mm = v;
#pragma unroll
  for (int off = 1; off <= 32; off <<= 1) mm = fmaxf(mm, __shfl_xor(mm, off));
  float e = act ? __expf(v - mm) : 0.f;
  float se = e;
#pragma unroll
  for (int off = 1; off <= 32; off <<= 1) se += __shfl_xor(se, off);
  if (act) out[(size_t)wid * 40 + lane] = v - mm - __logf(se);
}

// ---------------- launch ----------------
extern "C" void kernel_launch(void* const* d_in, const int* in_sizes, int n_in,
                              void* d_out, int out_size, void* d_ws, size_t ws_size,
                              hipStream_t stream) {
  const float* x   = (const float*)d_in[0];
  const int*   ei  = (const int*)d_in[1];
  const float* W0  = (const float*)d_in[2];
  const float* as0 = (const float*)d_in[3];
  const float* ad0 = (const float*)d_in[4];
  const float* b0  = (const float*)d_in[5];
  const float* W1  = (const float*)d_in[6];
  const float* as1 = (const float*)d_in[7];
  const float* ad1 = (const float*)d_in[8];
  const float* b1  = (const float*)d_in[9];
  const float* W2  = (const float*)d_in[10];
  const float* as2 = (const float*)d_in[11];
  const float* ad2 = (const float*)d_in[12];
  const float* b2  = (const float*)d_in[13];
  float* out = (float*)d_out;

  char* p = (char*)d_ws;
  auto take = [&](size_t bytes) {
    char* q = p;
    p += (bytes + 255) & ~(size_t)255;
    return (void*)q;
  };
  float* hbuf = (float*)take((size_t)NODES * 256 * 4);
  float* xbuf = (float*)take((size_t)NODES * 256 * 4);
  float* als  = (float*)take((size_t)NODES * 4 * 4);
  float* ald  = (float*)take((size_t)NODES * 4 * 4);
  int* ssrc   = (int*)take((size_t)TOT_E * 4);
  int* offs   = (int*)take((size_t)(NODES + 1) * 4);
  int* cur    = (int*)take((size_t)NODES * 4);
  int* cnt    = (int*)take((size_t)NODES * 4);

  // CSR build (dst-sorted edge list incl. self-loops)
  hipMemsetAsync(cnt, 0, (size_t)NODES * 4, stream);
  k_hist<<<2048, 256, 0, stream>>>(ei + NEDGES, cnt);
  k_scan<<<1, 1024, 0, stream>>>(cnt, offs);
  k_copy_cursor<<<(NODES + 255) / 256, 256, 0, stream>>>(offs, cur);
  k_scatter<<<2048, 256, 0, stream>>>(ei, ei + NEDGES, cur, ssrc);

  int nwb = (NODES * 64 + 255) / 256;  // wave-per-node blocks

  // layer 0
  dim3 g0((NODES + BM - 1) / BM, (256 + BN - 1) / BN);
  k_gemm<<<g0, 256, 0, stream>>>(x, W0, hbuf, NODES, 256, 128);
  k_alog4<<<nwb, 256, 0, stream>>>(hbuf, as0, ad0, als, ald);
  k_agg4<<<nwb, 256, 0, stream>>>(hbuf, als, ald, offs, ssrc, b0, xbuf);

  // layer 1
  k_gemm<<<g0, 256, 0, stream>>>(xbuf, W1, hbuf, NODES, 256, 256);
  k_alog4<<<nwb, 256, 0, stream>>>(hbuf, as1, ad1, als, ald);
  k_agg4<<<nwb, 256, 0, stream>>>(hbuf, als, ald, offs, ssrc, b1, xbuf);

  // layer 2
  dim3 g2((NODES + BM - 1) / BM, 1);
  k_gemm<<<g2, 256, 0, stream>>>(xbuf, W2, hbuf, NODES, 40, 256);
  k_alog1<<<nwb, 256, 0, stream>>>(hbuf, as2, ad2, als, ald);
  k_agg1<<<nwb, 256, 0, stream>>>(hbuf, als, ald, offs, ssrc, b2, out);
}

// Round 2
// 633.987 us; speedup vs baseline: 1.2132x; 1.2132x over previous
//
#include <hip/hip_runtime.h>
#include <math.h>

#define NODES 50000
#define NEDGES 800000
#define TOT_E (NEDGES + NODES)

typedef __attribute__((ext_vector_type(8))) short short8v;
typedef __attribute__((ext_vector_type(4))) float f32x4;

static __device__ __forceinline__ float lrelu(float z) {
  return z > 0.f ? z : 0.2f * z;
}
static __device__ __forceinline__ float b2f(ushort u) {
  union { uint i; float f; } v; v.i = ((uint)u) << 16; return v.f;
}
static __device__ __forceinline__ ushort f2b(float f) {
  union { float f; uint i; } v; v.f = f;
  uint r = v.i + 0x7fff + ((v.i >> 16) & 1);
  return (ushort)(r >> 16);
}

// ---------------- CSR build ----------------
__global__ void k_hist(const int* __restrict__ dst, int* __restrict__ counts) {
  int stride = gridDim.x * blockDim.x;
  for (int i = blockIdx.x * blockDim.x + threadIdx.x; i < TOT_E; i += stride) {
    int d = (i < NEDGES) ? dst[i] : (i - NEDGES);
    atomicAdd(&counts[d], 1);
  }
}

__global__ void k_scan(const int* __restrict__ counts, int* __restrict__ offs) {
  __shared__ int part[1024];
  const int n = NODES;
  int tid = threadIdx.x;
  int chunk = (n + 1023) / 1024;
  int b = tid * chunk;
  int e = min(b + chunk, n);
  int sum = 0;
  for (int i = b; i < e; ++i) sum += counts[i];
  part[tid] = sum;
  __syncthreads();
  for (int off = 1; off < 1024; off <<= 1) {
    int v = (tid >= off) ? part[tid - off] : 0;
    __syncthreads();
    part[tid] += v;
    __syncthreads();
  }
  int base = (tid == 0) ? 0 : part[tid - 1];
  for (int i = b; i < e; ++i) { offs[i] = base; base += counts[i]; }
  if (tid == 1023) offs[n] = base;
}

__global__ void k_copy_cursor(const int* __restrict__ offs, int* __restrict__ cur) {
  int i = blockIdx.x * blockDim.x + threadIdx.x;
  if (i < NODES) cur[i] = offs[i];
}

__global__ void k_scatter(const int* __restrict__ src, const int* __restrict__ dst,
                          int* __restrict__ cur, int* __restrict__ ssrc) {
  int stride = gridDim.x * blockDim.x;
  for (int i = blockIdx.x * blockDim.x + threadIdx.x; i < TOT_E; i += stride) {
    int s, d;
    if (i < NEDGES) { s = src[i]; d = dst[i]; } else { s = i - NEDGES; d = s; }
    int pos = atomicAdd(&cur[d], 1);
    ssrc[pos] = s;
  }
}

// ---------------- casts / packing ----------------
__global__ void k_cast4(const float* __restrict__ X, ushort* __restrict__ Xb, int total4) {
  int stride = gridDim.x * blockDim.x;
  for (int i = blockIdx.x * blockDim.x + threadIdx.x; i < total4; i += stride) {
    float4 v = *(const float4*)&X[i * 4];
    ushort4 o;
    o.x = f2b(v.x); o.y = f2b(v.y); o.z = f2b(v.z); o.w = f2b(v.w);
    *(ushort4*)&Xb[i * 4] = o;
  }
}

// Bpack[kf][nf][lane][8] = B[kf*32 + (lane>>4)*8 + i][nf*16 + (lane&15)]
__global__ void k_packB(const float* __restrict__ W, ushort* __restrict__ Bp,
                        int N, int NF, int total) {
  int idx = blockIdx.x * blockDim.x + threadIdx.x;
  if (idx >= total) return;
  int i = idx & 7;
  int lane = (idx >> 3) & 63;
  int rem = idx >> 9;
  int nf = rem % NF;
  int kf = rem / NF;
  int k = kf * 32 + (lane >> 4) * 8 + i;
  int col = nf * 16 + (lane & 15);
  float v = (col < N) ? W[(size_t)k * N + col] : 0.f;
  Bp[idx] = f2b(v);
}

// ---------------- MFMA GEMM: wave computes 16 rows x N cols ----------------
// A bf16 [M][K], Bpack fragment-order, H bf16 out [M][N]
template<int NF>
__global__ __launch_bounds__(256) void k_gemm_mfma(
    const ushort* __restrict__ A, const ushort* __restrict__ Bp,
    ushort* __restrict__ H, int M, int N, int K) {
  int wid = (blockIdx.x * blockDim.x + threadIdx.x) >> 6;
  int strip = wid * 16;
  if (strip >= M) return;
  int lane = threadIdx.x & 63;
  int lg = lane >> 4;   // k-group
  int lr = lane & 15;   // A row / B,D col within frag
  f32x4 acc[NF];
#pragma unroll
  for (int n = 0; n < NF; ++n) acc[n] = (f32x4){0.f, 0.f, 0.f, 0.f};
  const ushort* arow = A + (size_t)(strip + lr) * K + lg * 8;
  const ushort* bp = Bp + (size_t)lane * 8;
  int KF = K >> 5;
  for (int kf = 0; kf < KF; ++kf) {
    short8v af = *(const short8v*)(arow + kf * 32);
#pragma unroll
    for (int n = 0; n < NF; ++n) {
      short8v bf = *(const short8v*)(bp + (size_t)(kf * NF + n) * 512);
      acc[n] = __builtin_amdgcn_mfma_f32_16x16x32_bf16(af, bf, acc[n], 0, 0, 0);
    }
  }
#pragma unroll
  for (int n = 0; n < NF; ++n) {
    int col = n * 16 + lr;
    if (col >= N) continue;
#pragma unroll
    for (int r = 0; r < 4; ++r) {
      int row = strip + lg * 4 + r;
      H[(size_t)row * N + col] = f2b(acc[n][r]);
    }
  }
}

// ---------------- attention logits per node ----------------
// H=4, C=64
__global__ __launch_bounds__(256) void k_alog4(const ushort* __restrict__ hb,
    const float* __restrict__ a_s, const float* __restrict__ a_d,
    float* __restrict__ al_s, float* __restrict__ al_d) {
  int wid = (blockIdx.x * blockDim.x + threadIdx.x) >> 6;
  if (wid >= NODES) return;
  int lane = threadIdx.x & 63;
  ushort4 hv = *(const ushort4*)&hb[(size_t)wid * 256 + lane * 4];
  float h0 = b2f(hv.x), h1 = b2f(hv.y), h2 = b2f(hv.z), h3 = b2f(hv.w);
  float4 sv = *(const float4*)&a_s[lane * 4];
  float4 dv = *(const float4*)&a_d[lane * 4];
  float ps = h0 * sv.x + h1 * sv.y + h2 * sv.z + h3 * sv.w;
  float pd = h0 * dv.x + h1 * dv.y + h2 * dv.z + h3 * dv.w;
#pragma unroll
  for (int off = 1; off <= 8; off <<= 1) {
    ps += __shfl_xor(ps, off);
    pd += __shfl_xor(pd, off);
  }
  if ((lane & 15) == 0) {
    al_s[wid * 4 + (lane >> 4)] = ps;
    al_d[wid * 4 + (lane >> 4)] = pd;
  }
}

// H=1, C=40
__global__ __launch_bounds__(256) void k_alog1(const ushort* __restrict__ hb,
    const float* __restrict__ a_s, const float* __restrict__ a_d,
    float* __restrict__ al_s, float* __restrict__ al_d) {
  int wid = (blockIdx.x * blockDim.x + threadIdx.x) >> 6;
  if (wid >= NODES) return;
  int lane = threadIdx.x & 63;
  float ps = 0.f, pd = 0.f;
  if (lane < 40) {
    float hv = b2f(hb[(size_t)wid * 40 + lane]);
    ps = hv * a_s[lane];
    pd = hv * a_d[lane];
  }
#pragma unroll
  for (int off = 1; off <= 32; off <<= 1) {
    ps += __shfl_xor(ps, off);
    pd += __shfl_xor(pd, off);
  }
  if (lane == 0) { al_s[wid] = ps; al_d[wid] = pd; }
}

// ---------------- aggregation: wave per dst node ----------------
// layers 0/1: H=4, C=64, fused bias + ELU, bf16 in/out
__global__ __launch_bounds__(256) void k_agg4(const ushort* __restrict__ hb,
    const float* __restrict__ al_s, const float* __restrict__ al_d,
    const int* __restrict__ offs, const int* __restrict__ ssrc,
    const float* __restrict__ bias, ushort* __restrict__ outb) {
  int wid = (blockIdx.x * blockDim.x + threadIdx.x) >> 6;
  if (wid >= NODES) return;
  int lane = threadIdx.x & 63;
  int beg = offs[wid], end = offs[wid + 1];
  int h1 = lane >> 4;
  int es = lane & 15;
  float ald = al_d[wid * 4 + h1];

  float m = -1e30f, s = 0.f;
  for (int i = beg + es; i < end; i += 16) {
    int sv = ssrc[i];
    float z = lrelu(al_s[sv * 4 + h1] + ald);
    if (z > m) { s = s * __expf(m - z) + 1.f; m = z; }
    else s += __expf(z - m);
  }
#pragma unroll
  for (int off = 1; off <= 8; off <<= 1) {
    float mo = __shfl_xor(m, off), so = __shfl_xor(s, off);
    float mn = fmaxf(m, mo);
    s = s * __expf(m - mn) + so * __expf(mo - mn);
    m = mn;
  }
  float inv = 1.f / s;

  float4 acc = make_float4(0.f, 0.f, 0.f, 0.f);
  int cbase = lane * 4;
  for (int i = beg; i < end; ++i) {
    int sv = ssrc[i];
    float z = lrelu(al_s[sv * 4 + h1] + ald);
    float alpha = __expf(z - m) * inv;
    ushort4 hv = *(const ushort4*)&hb[(size_t)sv * 256 + cbase];
    acc.x += alpha * b2f(hv.x); acc.y += alpha * b2f(hv.y);
    acc.z += alpha * b2f(hv.z); acc.w += alpha * b2f(hv.w);
  }
  float4 bv = *(const float4*)&bias[cbase];
  float vx = acc.x + bv.x, vy = acc.y + bv.y, vz = acc.z + bv.z, vw = acc.w + bv.w;
  ushort4 o;
  o.x = f2b(vx > 0.f ? vx : __expf(vx) - 1.f);
  o.y = f2b(vy > 0.f ? vy : __expf(vy) - 1.f);
  o.z = f2b(vz > 0.f ? vz : __expf(vz) - 1.f);
  o.w = f2b(vw > 0.f ? vw : __expf(vw) - 1.f);
  *(ushort4*)&outb[(size_t)wid * 256 + cbase] = o;
}

// layer 2: H=1, C=40, fused bias + log_softmax, f32 final out
__global__ __launch_bounds__(256) void k_agg1(const ushort* __restrict__ hb,
    const float* __restrict__ al_s, const float* __restrict__ al_d,
    const int* __restrict__ offs, const int* __restrict__ ssrc,
    const float* __restrict__ bias, float* __restrict__ out) {
  int wid = (blockIdx.x * blockDim.x + threadIdx.x) >> 6;
  if (wid >= NODES) return;
  int lane = threadIdx.x & 63;
  int beg = offs[wid], end = offs[wid + 1];
  float ald = al_d[wid];

  float m = -1e30f, s = 0.f;
  for (int i = beg + lane; i < end; i += 64) {
    float z = lrelu(al_s[ssrc[i]] + ald);
    if (z > m) { s = s * __expf(m - z) + 1.f; m = z; }
    else s += __expf(z - m);
  }
#pragma unroll
  for (int off = 1; off <= 32; off <<= 1) {
    float mo = __shfl_xor(m, off), so = __shfl_xor(s, off);
    float mn = fmaxf(m, mo);
    s = s * __expf(m - mn) + so * __expf(mo - mn);
    m = mn;
  }
  float inv = 1.f / s;

  float acc = 0.f;
  bool act = lane < 40;
  for (int i = beg; i < end; ++i) {
    int sv = ssrc[i];
    float z = lrelu(al_s[sv] + ald);
    float alpha = __expf(z - m) * inv;
    if (act) acc += alpha * b2f(hb[(size_t)sv * 40 + lane]);
  }
  float v = act ? acc + bias[lane] : -1e30f;
  float mm = v;
#pragma unroll
  for (int off = 1; off <= 32; off <<= 1) mm = fmaxf(mm, __shfl_xor(mm, off));
  float e = act ? __expf(v - mm) : 0.f;
  float se = e;
#pragma unroll
  for (int off = 1; off <= 32; off <<= 1) se += __shfl_xor(se, off);
  if (act) out[(size_t)wid * 40 + lane] = v - mm - __logf(se);
}

// ---------------- launch ----------------
extern "C" void kernel_launch(void* const* d_in, const int* in_sizes, int n_in,
                              void* d_out, int out_size, void* d_ws, size_t ws_size,
                              hipStream_t stream) {
  const float* x   = (const float*)d_in[0];
  const int*   ei  = (const int*)d_in[1];
  const float* W0  = (const float*)d_in[2];
  const float* as0 = (const float*)d_in[3];
  const float* ad0 = (const float*)d_in[4];
  const float* b0  = (const float*)d_in[5];
  const float* W1  = (const float*)d_in[6];
  const float* as1 = (const float*)d_in[7];
  const float* ad1 = (const float*)d_in[8];
  const float* b1  = (const float*)d_in[9];
  const float* W2  = (const float*)d_in[10];
  const float* as2 = (const float*)d_in[11];
  const float* ad2 = (const float*)d_in[12];
  const float* b2  = (const float*)d_in[13];
  float* out = (float*)d_out;

  char* p = (char*)d_ws;
  auto take = [&](size_t bytes) {
    char* q = p;
    p += (bytes + 255) & ~(size_t)255;
    return (void*)q;
  };
  ushort* xb0 = (ushort*)take((size_t)NODES * 128 * 2);
  ushort* xb1 = (ushort*)take((size_t)NODES * 256 * 2);
  ushort* xb2 = (ushort*)take((size_t)NODES * 256 * 2);
  ushort* hb  = (ushort*)take((size_t)NODES * 256 * 2);
  float* als  = (float*)take((size_t)NODES * 4 * 4);
  float* ald  = (float*)take((size_t)NODES * 4 * 4);
  int* ssrc   = (int*)take((size_t)TOT_E * 4);
  int* offs   = (int*)take((size_t)(NODES + 1) * 4);
  int* cur    = (int*)take((size_t)NODES * 4);
  int* cnt    = (int*)take((size_t)NODES * 4);
  ushort* Bp0 = (ushort*)take((size_t)4 * 16 * 512 * 2);
  ushort* Bp1 = (ushort*)take((size_t)8 * 16 * 512 * 2);
  ushort* Bp2 = (ushort*)take((size_t)8 * 3 * 512 * 2);

  // CSR build (dst-sorted edge list incl. self-loops)
  hipMemsetAsync(cnt, 0, (size_t)NODES * 4, stream);
  k_hist<<<2048, 256, 0, stream>>>(ei + NEDGES, cnt);
  k_scan<<<1, 1024, 0, stream>>>(cnt, offs);
  k_copy_cursor<<<(NODES + 255) / 256, 256, 0, stream>>>(offs, cur);
  k_scatter<<<2048, 256, 0, stream>>>(ei, ei + NEDGES, cur, ssrc);

  // bf16 casts / weight packs
  k_cast4<<<2048, 256, 0, stream>>>(x, xb0, NODES * 128 / 4);
  {
    int t0 = 4 * 16 * 512;  k_packB<<<(t0 + 255) / 256, 256, 0, stream>>>(W0, Bp0, 256, 16, t0);
    int t1 = 8 * 16 * 512;  k_packB<<<(t1 + 255) / 256, 256, 0, stream>>>(W1, Bp1, 256, 16, t1);
    int t2 = 8 * 3 * 512;   k_packB<<<(t2 + 255) / 256, 256, 0, stream>>>(W2, Bp2, 40, 3, t2);
  }

  int nwb = (NODES * 64 + 255) / 256;       // wave-per-node blocks
  int ngb = (NODES / 16 + 3) / 4;           // gemm blocks (4 waves x 16 rows)

  // layer 0
  k_gemm_mfma<16><<<ngb, 256, 0, stream>>>(xb0, Bp0, hb, NODES, 256, 128);
  k_alog4<<<nwb, 256, 0, stream>>>(hb, as0, ad0, als, ald);
  k_agg4<<<nwb, 256, 0, stream>>>(hb, als, ald, offs, ssrc, b0, xb1);

  // layer 1
  k_gemm_mfma<16><<<ngb, 256, 0, stream>>>(xb1, Bp1, hb, NODES, 256, 256);
  k_alog4<<<nwb, 256, 0, stream>>>(hb, as1, ad1, als, ald);
  k_agg4<<<nwb, 256, 0, stream>>>(hb, als, ald, offs, ssrc, b1, xb2);

  // layer 2
  k_gemm_mfma<3><<<ngb, 256, 0, stream>>>(xb2, Bp2, hb, NODES, 40, 256);
  k_alog1<<<nwb, 256, 0, stream>>>(hb, as2, ad2, als, ald);
  k_agg1<<<nwb, 256, 0, stream>>>(hb, als, ald, offs, ssrc, b2, out);
}

// Round 3
// 527.494 us; speedup vs baseline: 1.4581x; 1.2019x over previous
//
#include <hip/hip_runtime.h>
#include <math.h>

#define NODES 50000
#define NEDGES 800000
#define TOT_E (NEDGES + NODES)

typedef __attribute__((ext_vector_type(8))) short short8v;
typedef __attribute__((ext_vector_type(4))) float f32x4;

static __device__ __forceinline__ float lrelu(float z) {
  return z > 0.f ? z : 0.2f * z;
}
static __device__ __forceinline__ float b2f(ushort u) {
  union { uint i; float f; } v; v.i = ((uint)u) << 16; return v.f;
}
static __device__ __forceinline__ ushort f2b(float f) {
  union { float f; uint i; } v; v.f = f;
  uint r = v.i + 0x7fff + ((v.i >> 16) & 1);
  return (ushort)(r >> 16);
}

// ---------------- CSR build ----------------
__global__ void k_hist(const int* __restrict__ dst, int* __restrict__ counts) {
  int stride = gridDim.x * blockDim.x;
  for (int i = blockIdx.x * blockDim.x + threadIdx.x; i < TOT_E; i += stride) {
    int d = (i < NEDGES) ? dst[i] : (i - NEDGES);
    atomicAdd(&counts[d], 1);
  }
}

__global__ void k_scan(const int* __restrict__ counts, int* __restrict__ offs,
                       int* __restrict__ cur) {
  __shared__ int part[1024];
  const int n = NODES;
  int tid = threadIdx.x;
  int chunk = (n + 1023) / 1024;
  int b = tid * chunk;
  int e = min(b + chunk, n);
  int sum = 0;
  for (int i = b; i < e; ++i) sum += counts[i];
  part[tid] = sum;
  __syncthreads();
  for (int off = 1; off < 1024; off <<= 1) {
    int v = (tid >= off) ? part[tid - off] : 0;
    __syncthreads();
    part[tid] += v;
    __syncthreads();
  }
  int base = (tid == 0) ? 0 : part[tid - 1];
  for (int i = b; i < e; ++i) { offs[i] = base; cur[i] = base; base += counts[i]; }
  if (tid == 1023) offs[n] = base;
}

__global__ void k_scatter(const int* __restrict__ src, const int* __restrict__ dst,
                          int* __restrict__ cur, int* __restrict__ ssrc) {
  int stride = gridDim.x * blockDim.x;
  for (int i = blockIdx.x * blockDim.x + threadIdx.x; i < TOT_E; i += stride) {
    int s, d;
    if (i < NEDGES) { s = src[i]; d = dst[i]; } else { s = i - NEDGES; d = s; }
    int pos = atomicAdd(&cur[d], 1);
    ssrc[pos] = s;
  }
}

// ---------------- casts / packing ----------------
__global__ void k_cast4(const float* __restrict__ X, ushort* __restrict__ Xb, int total4) {
  int stride = gridDim.x * blockDim.x;
  for (int i = blockIdx.x * blockDim.x + threadIdx.x; i < total4; i += stride) {
    float4 v = *(const float4*)&X[i * 4];
    ushort4 o;
    o.x = f2b(v.x); o.y = f2b(v.y); o.z = f2b(v.z); o.w = f2b(v.w);
    *(ushort4*)&Xb[i * 4] = o;
  }
}

// Bpack[kf][nf][lane][8] = B[kf*32 + (lane>>4)*8 + i][nf*16 + (lane&15)]
__global__ void k_packB(const float* __restrict__ W, ushort* __restrict__ Bp,
                        int N, int NF, int total) {
  int idx = blockIdx.x * blockDim.x + threadIdx.x;
  if (idx >= total) return;
  int i = idx & 7;
  int lane = (idx >> 3) & 63;
  int rem = idx >> 9;
  int nf = rem % NF;
  int kf = rem / NF;
  int k = kf * 32 + (lane >> 4) * 8 + i;
  int col = nf * 16 + (lane & 15);
  float v = (col < N) ? W[(size_t)k * N + col] : 0.f;
  Bp[idx] = f2b(v);
}

// ---------------- MFMA GEMM + fused attention logits ----------------
// wave computes 16 rows x N cols; epilogue writes bf16 H and per-row head logits
template<int NF, int HEADS>
__global__ __launch_bounds__(256) void k_gemm_mfma(
    const ushort* __restrict__ A, const ushort* __restrict__ Bp,
    ushort* __restrict__ H, const float* __restrict__ a_s, const float* __restrict__ a_d,
    float* __restrict__ al_s, float* __restrict__ al_d, int M, int N, int K) {
  int wid = (blockIdx.x * blockDim.x + threadIdx.x) >> 6;
  int strip = wid * 16;
  if (strip >= M) return;
  int lane = threadIdx.x & 63;
  int lg = lane >> 4;   // k-group / row group
  int lr = lane & 15;   // A row idx in frag, B/D col idx in frag
  f32x4 acc[NF];
#pragma unroll
  for (int n = 0; n < NF; ++n) acc[n] = (f32x4){0.f, 0.f, 0.f, 0.f};
  const ushort* arow = A + (size_t)(strip + lr) * K + lg * 8;
  const ushort* bp = Bp + (size_t)lane * 8;
  int KF = K >> 5;
  for (int kf = 0; kf < KF; ++kf) {
    short8v af = *(const short8v*)(arow + kf * 32);
#pragma unroll
    for (int n = 0; n < NF; ++n) {
      short8v bf = *(const short8v*)(bp + (size_t)(kf * NF + n) * 512);
      acc[n] = __builtin_amdgcn_mfma_f32_16x16x32_bf16(af, bf, acc[n], 0, 0, 0);
    }
  }
  // H write: D layout col = lr, row = lg*4 + r
#pragma unroll
  for (int n = 0; n < NF; ++n) {
    int col = n * 16 + lr;
    if (col >= N) continue;
#pragma unroll
    for (int r = 0; r < 4; ++r) {
      int row = strip + lg * 4 + r;
      H[(size_t)row * N + col] = f2b(acc[n][r]);
    }
  }
  // fused logits: al_s[row,h] = sum_{col in head h} C[row][col]*a_s_flat[col]
  float asc[NF], adc[NF];
#pragma unroll
  for (int n = 0; n < NF; ++n) {
    int col = n * 16 + lr;
    bool ok = col < N;
    asc[n] = ok ? a_s[col] : 0.f;
    adc[n] = ok ? a_d[col] : 0.f;
  }
  if (HEADS == 4) {
    float ps[16], pd[16];  // [h*4+r]
#pragma unroll
    for (int h = 0; h < 4; ++h)
#pragma unroll
      for (int r = 0; r < 4; ++r) {
        float s = 0.f, d = 0.f;
#pragma unroll
        for (int j = 0; j < 4; ++j) {
          int n = h * 4 + j;
          s += acc[n][r] * asc[n];
          d += acc[n][r] * adc[n];
        }
        ps[h * 4 + r] = s; pd[h * 4 + r] = d;
      }
#pragma unroll
    for (int off = 1; off <= 8; off <<= 1)
#pragma unroll
      for (int t = 0; t < 16; ++t) {
        ps[t] += __shfl_xor(ps[t], off);
        pd[t] += __shfl_xor(pd[t], off);
      }
    int h = lr >> 2, r = lr & 3;
    int row = strip + lg * 4 + r;
    al_s[row * 4 + h] = ps[lr];
    al_d[row * 4 + h] = pd[lr];
  } else {
    float ps[4], pd[4];
#pragma unroll
    for (int r = 0; r < 4; ++r) {
      float s = 0.f, d = 0.f;
#pragma unroll
      for (int n = 0; n < NF; ++n) {
        s += acc[n][r] * asc[n];
        d += acc[n][r] * adc[n];
      }
      ps[r] = s; pd[r] = d;
    }
#pragma unroll
    for (int off = 1; off <= 8; off <<= 1)
#pragma unroll
      for (int t = 0; t < 4; ++t) {
        ps[t] += __shfl_xor(ps[t], off);
        pd[t] += __shfl_xor(pd[t], off);
      }
    if (lr < 4) {
      int row = strip + lg * 4 + lr;
      al_s[row] = ps[lr];
      al_d[row] = pd[lr];
    }
  }
}

// ---------------- aggregation: wave per dst node ----------------
// layers 0/1: H=4, C=64; phase2 handles 2 edges/iter (ushort8 per lane)
__global__ __launch_bounds__(256) void k_agg4(const ushort* __restrict__ hb,
    const float* __restrict__ al_s, const float* __restrict__ al_d,
    const int* __restrict__ offs, const int* __restrict__ ssrc,
    const float* __restrict__ bias, ushort* __restrict__ outb) {
  int wid = (blockIdx.x * blockDim.x + threadIdx.x) >> 6;
  if (wid >= NODES) return;
  int lane = threadIdx.x & 63;
  int beg = offs[wid], end = offs[wid + 1];
  int h1 = lane >> 4;
  int es = lane & 15;
  float ald = al_d[wid * 4 + h1];

  // phase 1: online softmax stats, 16-lane group per head
  float m = -1e30f, s = 0.f;
  for (int i = beg + es; i < end; i += 16) {
    int sv = ssrc[i];
    float z = lrelu(al_s[sv * 4 + h1] + ald);
    if (z > m) { s = s * __expf(m - z) + 1.f; m = z; }
    else s += __expf(z - m);
  }
#pragma unroll
  for (int off = 1; off <= 8; off <<= 1) {
    float mo = __shfl_xor(m, off), so = __shfl_xor(s, off);
    float mn = fmaxf(m, mo);
    s = s * __expf(m - mn) + so * __expf(mo - mn);
    m = mn;
  }
  float inv = 1.f / s;

  // phase 2: 2 edges per iteration; lane = (half, channel-octet)
  int half = lane >> 5;      // edge parity
  int cl = lane & 31;        // channel octet: channels cl*8 .. cl*8+7
  int hh = cl >> 3;          // head of this octet
  int srcl = hh * 16;        // lane holding phase-1 stats for head hh
  float mh = __shfl(m, srcl);
  float invh = __shfl(inv, srcl);
  float aldh = __shfl(ald, srcl);
  float acc[8] = {0.f, 0.f, 0.f, 0.f, 0.f, 0.f, 0.f, 0.f};
  for (int i = beg + half; i < end; i += 2) {
    int sv = ssrc[i];
    float z = lrelu(al_s[sv * 4 + hh] + aldh);
    float alpha = __expf(z - mh) * invh;
    short8v hv = *(const short8v*)(hb + (size_t)sv * 256 + cl * 8);
#pragma unroll
    for (int j = 0; j < 8; ++j) acc[j] += alpha * b2f((ushort)hv[j]);
  }
#pragma unroll
  for (int j = 0; j < 8; ++j) acc[j] += __shfl_xor(acc[j], 32);
  if (half == 0) {
    short8v o;
#pragma unroll
    for (int j = 0; j < 8; ++j) {
      float v = acc[j] + bias[cl * 8 + j];
      o[j] = (short)f2b(v > 0.f ? v : __expf(v) - 1.f);
    }
    *(short8v*)(outb + (size_t)wid * 256 + cl * 8) = o;
  }
}

// layer 2: H=1, C=40; phase2 handles 4 edges/iter (ushort4 per lane, 10 lanes/edge)
__global__ __launch_bounds__(256) void k_agg1(const ushort* __restrict__ hb,
    const float* __restrict__ al_s, const float* __restrict__ al_d,
    const int* __restrict__ offs, const int* __restrict__ ssrc,
    const float* __restrict__ bias, float* __restrict__ out) {
  int wid = (blockIdx.x * blockDim.x + threadIdx.x) >> 6;
  if (wid >= NODES) return;
  int lane = threadIdx.x & 63;
  int beg = offs[wid], end = offs[wid + 1];
  float ald = al_d[wid];

  // phase 1: 64-lane strided online softmax
  float m = -1e30f, s = 0.f;
  for (int i = beg + lane; i < end; i += 64) {
    float z = lrelu(al_s[ssrc[i]] + ald);
    if (z > m) { s = s * __expf(m - z) + 1.f; m = z; }
    else s += __expf(z - m);
  }
#pragma unroll
  for (int off = 1; off <= 32; off <<= 1) {
    float mo = __shfl_xor(m, off), so = __shfl_xor(s, off);
    float mn = fmaxf(m, mo);
    s = s * __expf(m - mn) + so * __expf(mo - mn);
    m = mn;
  }
  float inv = 1.f / s;

  // phase 2: lane = (edge slot e, channel quad q); channels q*4..q*4+3 (q<10)
  int e = lane >> 4;
  int q = lane & 15;
  bool act = q < 10;
  float acc[4] = {0.f, 0.f, 0.f, 0.f};
  for (int i = beg + e; i < end; i += 4) {
    int sv = ssrc[i];
    float z = lrelu(al_s[sv] + ald);
    float alpha = __expf(z - m) * inv;
    if (act) {
      ushort4 hv = *(const ushort4*)&hb[(size_t)sv * 40 + q * 4];
      acc[0] += alpha * b2f(hv.x); acc[1] += alpha * b2f(hv.y);
      acc[2] += alpha * b2f(hv.z); acc[3] += alpha * b2f(hv.w);
    }
  }
#pragma unroll
  for (int j = 0; j < 4; ++j) {
    acc[j] += __shfl_xor(acc[j], 16);
    acc[j] += __shfl_xor(acc[j], 32);
  }
  // bias + log_softmax over the 40 channels (quads live on q<10, all e-groups identical)
  float v[4];
  float mm = -1e30f;
  if (act) {
#pragma unroll
    for (int j = 0; j < 4; ++j) {
      v[j] = acc[j] + bias[q * 4 + j];
      mm = fmaxf(mm, v[j]);
    }
  }
#pragma unroll
  for (int off = 1; off <= 8; off <<= 1) mm = fmaxf(mm, __shfl_xor(mm, off));
  float se = 0.f;
  if (act) {
#pragma unroll
    for (int j = 0; j < 4; ++j) se += __expf(v[j] - mm);
  }
#pragma unroll
  for (int off = 1; off <= 8; off <<= 1) se += __shfl_xor(se, off);
  if (act && e == 0) {
    float lse = mm + __logf(se);
    float4 o;
    o.x = v[0] - lse; o.y = v[1] - lse; o.z = v[2] - lse; o.w = v[3] - lse;
    *(float4*)&out[(size_t)wid * 40 + q * 4] = o;
  }
}

// ---------------- launch ----------------
extern "C" void kernel_launch(void* const* d_in, const int* in_sizes, int n_in,
                              void* d_out, int out_size, void* d_ws, size_t ws_size,
                              hipStream_t stream) {
  const float* x   = (const float*)d_in[0];
  const int*   ei  = (const int*)d_in[1];
  const float* W0  = (const float*)d_in[2];
  const float* as0 = (const float*)d_in[3];
  const float* ad0 = (const float*)d_in[4];
  const float* b0  = (const float*)d_in[5];
  const float* W1  = (const float*)d_in[6];
  const float* as1 = (const float*)d_in[7];
  const float* ad1 = (const float*)d_in[8];
  const float* b1  = (const float*)d_in[9];
  const float* W2  = (const float*)d_in[10];
  const float* as2 = (const float*)d_in[11];
  const float* ad2 = (const float*)d_in[12];
  const float* b2  = (const float*)d_in[13];
  float* out = (float*)d_out;

  char* p = (char*)d_ws;
  auto take = [&](size_t bytes) {
    char* q = p;
    p += (bytes + 255) & ~(size_t)255;
    return (void*)q;
  };
  ushort* xb0 = (ushort*)take((size_t)NODES * 128 * 2);
  ushort* xb1 = (ushort*)take((size_t)NODES * 256 * 2);
  ushort* xb2 = (ushort*)take((size_t)NODES * 256 * 2);
  ushort* hb  = (ushort*)take((size_t)NODES * 256 * 2);
  float* als  = (float*)take((size_t)NODES * 4 * 4);
  float* ald  = (float*)take((size_t)NODES * 4 * 4);
  int* ssrc   = (int*)take((size_t)TOT_E * 4);
  int* offs   = (int*)take((size_t)(NODES + 1) * 4);
  int* cur    = (int*)take((size_t)NODES * 4);
  int* cnt    = (int*)take((size_t)NODES * 4);
  ushort* Bp0 = (ushort*)take((size_t)4 * 16 * 512 * 2);
  ushort* Bp1 = (ushort*)take((size_t)8 * 16 * 512 * 2);
  ushort* Bp2 = (ushort*)take((size_t)8 * 3 * 512 * 2);

  // CSR build (dst-sorted edge list incl. self-loops)
  hipMemsetAsync(cnt, 0, (size_t)NODES * 4, stream);
  k_hist<<<2048, 256, 0, stream>>>(ei + NEDGES, cnt);
  k_scan<<<1, 1024, 0, stream>>>(cnt, offs, cur);
  k_scatter<<<2048, 256, 0, stream>>>(ei, ei + NEDGES, cur, ssrc);

  // bf16 casts / weight packs
  k_cast4<<<2048, 256, 0, stream>>>(x, xb0, NODES * 128 / 4);
  {
    int t0 = 4 * 16 * 512;  k_packB<<<(t0 + 255) / 256, 256, 0, stream>>>(W0, Bp0, 256, 16, t0);
    int t1 = 8 * 16 * 512;  k_packB<<<(t1 + 255) / 256, 256, 0, stream>>>(W1, Bp1, 256, 16, t1);
    int t2 = 8 * 3 * 512;   k_packB<<<(t2 + 255) / 256, 256, 0, stream>>>(W2, Bp2, 40, 3, t2);
  }

  int nwb = (NODES * 64 + 255) / 256;       // wave-per-node blocks
  int ngb = (NODES / 16 + 3) / 4;           // gemm blocks (4 waves x 16 rows)

  // layer 0
  k_gemm_mfma<16, 4><<<ngb, 256, 0, stream>>>(xb0, Bp0, hb, as0, ad0, als, ald, NODES, 256, 128);
  k_agg4<<<nwb, 256, 0, stream>>>(hb, als, ald, offs, ssrc, b0, xb1);

  // layer 1
  k_gemm_mfma<16, 4><<<ngb, 256, 0, stream>>>(xb1, Bp1, hb, as1, ad1, als, ald, NODES, 256, 256);
  k_agg4<<<nwb, 256, 0, stream>>>(hb, als, ald, offs, ssrc, b1, xb2);

  // layer 2
  k_gemm_mfma<3, 1><<<ngb, 256, 0, stream>>>(xb2, Bp2, hb, as2, ad2, als, ald, NODES, 40, 256);
  k_agg1<<<nwb, 256, 0, stream>>>(hb, als, ald, offs, ssrc, b2, out);
}

// Round 4
// 413.536 us; speedup vs baseline: 1.8599x; 1.2756x over previous
//
#include <hip/hip_runtime.h>
#include <math.h>

#define NODES 50000
#define NEDGES 800000
#define TOT_E (NEDGES + NODES)
#define SCAN_B 256
#define SCAN_NB ((NODES + SCAN_B - 1) / SCAN_B)

typedef __attribute__((ext_vector_type(8))) short short8v;
typedef __attribute__((ext_vector_type(4))) float f32x4;

static __device__ __forceinline__ float lrelu(float z) {
  return z > 0.f ? z : 0.2f * z;
}
static __device__ __forceinline__ float b2f(ushort u) {
  union { uint i; float f; } v; v.i = ((uint)u) << 16; return v.f;
}
static __device__ __forceinline__ ushort f2b(float f) {
  union { float f; uint i; } v; v.f = f;
  uint r = v.i + 0x7fff + ((v.i >> 16) & 1);
  return (ushort)(r >> 16);
}

// ---------------- CSR build ----------------
__global__ void k_hist(const int* __restrict__ dst, int* __restrict__ counts) {
  int stride = gridDim.x * blockDim.x;
  for (int i = blockIdx.x * blockDim.x + threadIdx.x; i < TOT_E; i += stride) {
    int d = (i < NEDGES) ? dst[i] : (i - NEDGES);
    atomicAdd(&counts[d], 1);
  }
}

// pass 1: per-block sum of 256 counts
__global__ __launch_bounds__(SCAN_B) void k_scan_red(const int* __restrict__ counts,
                                                     int* __restrict__ bsum) {
  __shared__ int sm[SCAN_B];
  int idx = blockIdx.x * SCAN_B + threadIdx.x;
  int v = (idx < NODES) ? counts[idx] : 0;
  sm[threadIdx.x] = v;
  __syncthreads();
  for (int off = SCAN_B / 2; off > 0; off >>= 1) {
    if (threadIdx.x < off) sm[threadIdx.x] += sm[threadIdx.x + off];
    __syncthreads();
  }
  if (threadIdx.x == 0) bsum[blockIdx.x] = sm[0];
}

// pass 2: single block exclusive-scans the partials
__global__ __launch_bounds__(256) void k_scan_part(const int* __restrict__ bsum,
                                                   int* __restrict__ bpre) {
  __shared__ int sm[256];
  int tid = threadIdx.x;
  int v = (tid < SCAN_NB) ? bsum[tid] : 0;
  sm[tid] = v;
  __syncthreads();
  for (int off = 1; off < 256; off <<= 1) {
    int t = (tid >= off) ? sm[tid - off] : 0;
    __syncthreads();
    sm[tid] += t;
    __syncthreads();
  }
  if (tid < SCAN_NB) bpre[tid] = sm[tid] - v;  // exclusive
}

// pass 3: per-block exclusive scan + base, emit offs & cur
__global__ __launch_bounds__(SCAN_B) void k_scan_emit(const int* __restrict__ counts,
    const int* __restrict__ bpre, int* __restrict__ offs, int* __restrict__ cur) {
  __shared__ int sm[SCAN_B];
  int idx = blockIdx.x * SCAN_B + threadIdx.x;
  int tid = threadIdx.x;
  int v = (idx < NODES) ? counts[idx] : 0;
  sm[tid] = v;
  __syncthreads();
  for (int off = 1; off < SCAN_B; off <<= 1) {
    int t = (tid >= off) ? sm[tid - off] : 0;
    __syncthreads();
    sm[tid] += t;
    __syncthreads();
  }
  int base = bpre[blockIdx.x];
  int excl = base + sm[tid] - v;
  if (idx < NODES) { offs[idx] = excl; cur[idx] = excl; }
  if (idx == NODES - 1) offs[NODES] = excl + v;
}

__global__ void k_scatter(const int* __restrict__ src, const int* __restrict__ dst,
                          int* __restrict__ cur, int* __restrict__ ssrc) {
  int stride = gridDim.x * blockDim.x;
  for (int i = blockIdx.x * blockDim.x + threadIdx.x; i < TOT_E; i += stride) {
    int s, d;
    if (i < NEDGES) { s = src[i]; d = dst[i]; } else { s = i - NEDGES; d = s; }
    int pos = atomicAdd(&cur[d], 1);
    ssrc[pos] = s;
  }
}

// ---------------- casts / packing ----------------
__global__ void k_cast4(const float* __restrict__ X, ushort* __restrict__ Xb, int total4) {
  int stride = gridDim.x * blockDim.x;
  for (int i = blockIdx.x * blockDim.x + threadIdx.x; i < total4; i += stride) {
    float4 v = *(const float4*)&X[i * 4];
    ushort4 o;
    o.x = f2b(v.x); o.y = f2b(v.y); o.z = f2b(v.z); o.w = f2b(v.w);
    *(ushort4*)&Xb[i * 4] = o;
  }
}

// Bpack[kf][nf][lane][8] = B[kf*32 + (lane>>4)*8 + i][nf*16 + (lane&15)]
__global__ void k_packB(const float* __restrict__ W, ushort* __restrict__ Bp,
                        int N, int NF, int total) {
  int idx = blockIdx.x * blockDim.x + threadIdx.x;
  if (idx >= total) return;
  int i = idx & 7;
  int lane = (idx >> 3) & 63;
  int rem = idx >> 9;
  int nf = rem % NF;
  int kf = rem / NF;
  int k = kf * 32 + (lane >> 4) * 8 + i;
  int col = nf * 16 + (lane & 15);
  float v = (col < N) ? W[(size_t)k * N + col] : 0.f;
  Bp[idx] = f2b(v);
}

// ---------------- MFMA GEMM + fused attention logits ----------------
template<int NF, int HEADS>
__global__ __launch_bounds__(256) void k_gemm_mfma(
    const ushort* __restrict__ A, const ushort* __restrict__ Bp,
    ushort* __restrict__ H, const float* __restrict__ a_s, const float* __restrict__ a_d,
    float* __restrict__ al_s, float* __restrict__ al_d, int M, int N, int K) {
  int wid = (blockIdx.x * blockDim.x + threadIdx.x) >> 6;
  int strip = wid * 16;
  if (strip >= M) return;
  int lane = threadIdx.x & 63;
  int lg = lane >> 4;   // k-group / row group
  int lr = lane & 15;   // A row idx in frag, B/D col idx in frag
  f32x4 acc[NF];
#pragma unroll
  for (int n = 0; n < NF; ++n) acc[n] = (f32x4){0.f, 0.f, 0.f, 0.f};
  const ushort* arow = A + (size_t)(strip + lr) * K + lg * 8;
  const ushort* bp = Bp + (size_t)lane * 8;
  int KF = K >> 5;
  for (int kf = 0; kf < KF; ++kf) {
    short8v af = *(const short8v*)(arow + kf * 32);
#pragma unroll
    for (int n = 0; n < NF; ++n) {
      short8v bf = *(const short8v*)(bp + (size_t)(kf * NF + n) * 512);
      acc[n] = __builtin_amdgcn_mfma_f32_16x16x32_bf16(af, bf, acc[n], 0, 0, 0);
    }
  }
  // H write: D layout col = lr, row = lg*4 + r
#pragma unroll
  for (int n = 0; n < NF; ++n) {
    int col = n * 16 + lr;
    if (col >= N) continue;
#pragma unroll
    for (int r = 0; r < 4; ++r) {
      int row = strip + lg * 4 + r;
      H[(size_t)row * N + col] = f2b(acc[n][r]);
    }
  }
  // fused logits
  float asc[NF], adc[NF];
#pragma unroll
  for (int n = 0; n < NF; ++n) {
    int col = n * 16 + lr;
    bool ok = col < N;
    asc[n] = ok ? a_s[col] : 0.f;
    adc[n] = ok ? a_d[col] : 0.f;
  }
  if (HEADS == 4) {
    float ps[16], pd[16];  // [h*4+r]
#pragma unroll
    for (int h = 0; h < 4; ++h)
#pragma unroll
      for (int r = 0; r < 4; ++r) {
        float s = 0.f, d = 0.f;
#pragma unroll
        for (int j = 0; j < 4; ++j) {
          int n = h * 4 + j;
          s += acc[n][r] * asc[n];
          d += acc[n][r] * adc[n];
        }
        ps[h * 4 + r] = s; pd[h * 4 + r] = d;
      }
#pragma unroll
    for (int off = 1; off <= 8; off <<= 1)
#pragma unroll
      for (int t = 0; t < 16; ++t) {
        ps[t] += __shfl_xor(ps[t], off);
        pd[t] += __shfl_xor(pd[t], off);
      }
    int h = lr >> 2, r = lr & 3;
    int row = strip + lg * 4 + r;
    al_s[row * 4 + h] = ps[lr];
    al_d[row * 4 + h] = pd[lr];
  } else {
    float ps[4], pd[4];
#pragma unroll
    for (int r = 0; r < 4; ++r) {
      float s = 0.f, d = 0.f;
#pragma unroll
      for (int n = 0; n < NF; ++n) {
        s += acc[n][r] * asc[n];
        d += acc[n][r] * adc[n];
      }
      ps[r] = s; pd[r] = d;
    }
#pragma unroll
    for (int off = 1; off <= 8; off <<= 1)
#pragma unroll
      for (int t = 0; t < 4; ++t) {
        ps[t] += __shfl_xor(ps[t], off);
        pd[t] += __shfl_xor(pd[t], off);
      }
    if (lr < 4) {
      int row = strip + lg * 4 + lr;
      al_s[row] = ps[lr];
      al_d[row] = pd[lr];
    }
  }
}

// ---------------- aggregation: wave per dst node ----------------
// layers 0/1: H=4, C=64; phase2 2 edges/iter, manually unrolled x2
__global__ __launch_bounds__(256) void k_agg4(const ushort* __restrict__ hb,
    const float* __restrict__ al_s, const float* __restrict__ al_d,
    const int* __restrict__ offs, const int* __restrict__ ssrc,
    const float* __restrict__ bias, ushort* __restrict__ outb) {
  int wid = (blockIdx.x * blockDim.x + threadIdx.x) >> 6;
  if (wid >= NODES) return;
  int lane = threadIdx.x & 63;
  int beg = offs[wid], end = offs[wid + 1];
  int h1 = lane >> 4;
  int es = lane & 15;
  float ald = al_d[wid * 4 + h1];

  // phase 1: online softmax stats, 16-lane group per head
  float m = -1e30f, s = 0.f;
  for (int i = beg + es; i < end; i += 16) {
    int sv = ssrc[i];
    float z = lrelu(al_s[sv * 4 + h1] + ald);
    if (z > m) { s = s * __expf(m - z) + 1.f; m = z; }
    else s += __expf(z - m);
  }
#pragma unroll
  for (int off = 1; off <= 8; off <<= 1) {
    float mo = __shfl_xor(m, off), so = __shfl_xor(s, off);
    float mn = fmaxf(m, mo);
    s = s * __expf(m - mn) + so * __expf(mo - mn);
    m = mn;
  }
  float inv = 1.f / s;

  // phase 2: lane = (half, channel-octet); 2 edges per trip, unrolled x2
  int half = lane >> 5;
  int cl = lane & 31;
  int hh = cl >> 3;
  int srcl = hh * 16;
  float mh = __shfl(m, srcl);
  float invh = __shfl(inv, srcl);
  float aldh = __shfl(ald, srcl);
  float acc[8] = {0.f, 0.f, 0.f, 0.f, 0.f, 0.f, 0.f, 0.f};
  int i = beg + half;
  for (; i + 2 < end; i += 4) {
    int sv0 = ssrc[i], sv1 = ssrc[i + 2];
    float z0 = lrelu(al_s[sv0 * 4 + hh] + aldh);
    float z1 = lrelu(al_s[sv1 * 4 + hh] + aldh);
    float a0 = __expf(z0 - mh) * invh;
    float a1 = __expf(z1 - mh) * invh;
    short8v hv0 = *(const short8v*)(hb + (size_t)sv0 * 256 + cl * 8);
    short8v hv1 = *(const short8v*)(hb + (size_t)sv1 * 256 + cl * 8);
#pragma unroll
    for (int j = 0; j < 8; ++j) acc[j] += a0 * b2f((ushort)hv0[j]);
#pragma unroll
    for (int j = 0; j < 8; ++j) acc[j] += a1 * b2f((ushort)hv1[j]);
  }
  for (; i < end; i += 2) {
    int sv = ssrc[i];
    float z = lrelu(al_s[sv * 4 + hh] + aldh);
    float alpha = __expf(z - mh) * invh;
    short8v hv = *(const short8v*)(hb + (size_t)sv * 256 + cl * 8);
#pragma unroll
    for (int j = 0; j < 8; ++j) acc[j] += alpha * b2f((ushort)hv[j]);
  }
#pragma unroll
  for (int j = 0; j < 8; ++j) acc[j] += __shfl_xor(acc[j], 32);
  if (half == 0) {
    short8v o;
#pragma unroll
    for (int j = 0; j < 8; ++j) {
      float v = acc[j] + bias[cl * 8 + j];
      o[j] = (short)f2b(v > 0.f ? v : __expf(v) - 1.f);
    }
    *(short8v*)(outb + (size_t)wid * 256 + cl * 8) = o;
  }
}

// layer 2: H=1, C=40; phase2 4 edges/iter, unrolled x2
__global__ __launch_bounds__(256) void k_agg1(const ushort* __restrict__ hb,
    const float* __restrict__ al_s, const float* __restrict__ al_d,
    const int* __restrict__ offs, const int* __restrict__ ssrc,
    const float* __restrict__ bias, float* __restrict__ out) {
  int wid = (blockIdx.x * blockDim.x + threadIdx.x) >> 6;
  if (wid >= NODES) return;
  int lane = threadIdx.x & 63;
  int beg = offs[wid], end = offs[wid + 1];
  float ald = al_d[wid];

  float m = -1e30f, s = 0.f;
  for (int i = beg + lane; i < end; i += 64) {
    float z = lrelu(al_s[ssrc[i]] + ald);
    if (z > m) { s = s * __expf(m - z) + 1.f; m = z; }
    else s += __expf(z - m);
  }
#pragma unroll
  for (int off = 1; off <= 32; off <<= 1) {
    float mo = __shfl_xor(m, off), so = __shfl_xor(s, off);
    float mn = fmaxf(m, mo);
    s = s * __expf(m - mn) + so * __expf(mo - mn);
    m = mn;
  }
  float inv = 1.f / s;

  int e = lane >> 4;
  int q = lane & 15;
  bool act = q < 10;
  float acc[4] = {0.f, 0.f, 0.f, 0.f};
  int i = beg + e;
  for (; i + 4 < end; i += 8) {
    int sv0 = ssrc[i], sv1 = ssrc[i + 4];
    float z0 = lrelu(al_s[sv0] + ald);
    float z1 = lrelu(al_s[sv1] + ald);
    float a0 = __expf(z0 - m) * inv;
    float a1 = __expf(z1 - m) * inv;
    if (act) {
      ushort4 hv0 = *(const ushort4*)&hb[(size_t)sv0 * 40 + q * 4];
      ushort4 hv1 = *(const ushort4*)&hb[(size_t)sv1 * 40 + q * 4];
      acc[0] += a0 * b2f(hv0.x) + a1 * b2f(hv1.x);
      acc[1] += a0 * b2f(hv0.y) + a1 * b2f(hv1.y);
      acc[2] += a0 * b2f(hv0.z) + a1 * b2f(hv1.z);
      acc[3] += a0 * b2f(hv0.w) + a1 * b2f(hv1.w);
    }
  }
  for (; i < end; i += 4) {
    int sv = ssrc[i];
    float z = lrelu(al_s[sv] + ald);
    float alpha = __expf(z - m) * inv;
    if (act) {
      ushort4 hv = *(const ushort4*)&hb[(size_t)sv * 40 + q * 4];
      acc[0] += alpha * b2f(hv.x); acc[1] += alpha * b2f(hv.y);
      acc[2] += alpha * b2f(hv.z); acc[3] += alpha * b2f(hv.w);
    }
  }
#pragma unroll
  for (int j = 0; j < 4; ++j) {
    acc[j] += __shfl_xor(acc[j], 16);
    acc[j] += __shfl_xor(acc[j], 32);
  }
  float v[4];
  float mm = -1e30f;
  if (act) {
#pragma unroll
    for (int j = 0; j < 4; ++j) {
      v[j] = acc[j] + bias[q * 4 + j];
      mm = fmaxf(mm, v[j]);
    }
  }
#pragma unroll
  for (int off = 1; off <= 8; off <<= 1) mm = fmaxf(mm, __shfl_xor(mm, off));
  float se = 0.f;
  if (act) {
#pragma unroll
    for (int j = 0; j < 4; ++j) se += __expf(v[j] - mm);
  }
#pragma unroll
  for (int off = 1; off <= 8; off <<= 1) se += __shfl_xor(se, off);
  if (act && e == 0) {
    float lse = mm + __logf(se);
    float4 o;
    o.x = v[0] - lse; o.y = v[1] - lse; o.z = v[2] - lse; o.w = v[3] - lse;
    *(float4*)&out[(size_t)wid * 40 + q * 4] = o;
  }
}

// ---------------- launch ----------------
extern "C" void kernel_launch(void* const* d_in, const int* in_sizes, int n_in,
                              void* d_out, int out_size, void* d_ws, size_t ws_size,
                              hipStream_t stream) {
  const float* x   = (const float*)d_in[0];
  const int*   ei  = (const int*)d_in[1];
  const float* W0  = (const float*)d_in[2];
  const float* as0 = (const float*)d_in[3];
  const float* ad0 = (const float*)d_in[4];
  const float* b0  = (const float*)d_in[5];
  const float* W1  = (const float*)d_in[6];
  const float* as1 = (const float*)d_in[7];
  const float* ad1 = (const float*)d_in[8];
  const float* b1  = (const float*)d_in[9];
  const float* W2  = (const float*)d_in[10];
  const float* as2 = (const float*)d_in[11];
  const float* ad2 = (const float*)d_in[12];
  const float* b2  = (const float*)d_in[13];
  float* out = (float*)d_out;

  char* p = (char*)d_ws;
  auto take = [&](size_t bytes) {
    char* q = p;
    p += (bytes + 255) & ~(size_t)255;
    return (void*)q;
  };
  ushort* xb0 = (ushort*)take((size_t)NODES * 128 * 2);
  ushort* xb1 = (ushort*)take((size_t)NODES * 256 * 2);
  ushort* xb2 = (ushort*)take((size_t)NODES * 256 * 2);
  ushort* hb  = (ushort*)take((size_t)NODES * 256 * 2);
  float* als  = (float*)take((size_t)NODES * 4 * 4);
  float* ald  = (float*)take((size_t)NODES * 4 * 4);
  int* ssrc   = (int*)take((size_t)TOT_E * 4);
  int* offs   = (int*)take((size_t)(NODES + 1) * 4);
  int* cur    = (int*)take((size_t)NODES * 4);
  int* cnt    = (int*)take((size_t)NODES * 4);
  int* bsum   = (int*)take((size_t)SCAN_NB * 4);
  int* bpre   = (int*)take((size_t)SCAN_NB * 4);
  ushort* Bp0 = (ushort*)take((size_t)4 * 16 * 512 * 2);
  ushort* Bp1 = (ushort*)take((size_t)8 * 16 * 512 * 2);
  ushort* Bp2 = (ushort*)take((size_t)8 * 3 * 512 * 2);

  // CSR build (dst-sorted edge list incl. self-loops)
  hipMemsetAsync(cnt, 0, (size_t)NODES * 4, stream);
  k_hist<<<2048, 256, 0, stream>>>(ei + NEDGES, cnt);
  k_scan_red<<<SCAN_NB, SCAN_B, 0, stream>>>(cnt, bsum);
  k_scan_part<<<1, 256, 0, stream>>>(bsum, bpre);
  k_scan_emit<<<SCAN_NB, SCAN_B, 0, stream>>>(cnt, bpre, offs, cur);
  k_scatter<<<2048, 256, 0, stream>>>(ei, ei + NEDGES, cur, ssrc);

  // bf16 casts / weight packs
  k_cast4<<<2048, 256, 0, stream>>>(x, xb0, NODES * 128 / 4);
  {
    int t0 = 4 * 16 * 512;  k_packB<<<(t0 + 255) / 256, 256, 0, stream>>>(W0, Bp0, 256, 16, t0);
    int t1 = 8 * 16 * 512;  k_packB<<<(t1 + 255) / 256, 256, 0, stream>>>(W1, Bp1, 256, 16, t1);
    int t2 = 8 * 3 * 512;   k_packB<<<(t2 + 255) / 256, 256, 0, stream>>>(W2, Bp2, 40, 3, t2);
  }

  int nwb = (NODES * 64 + 255) / 256;       // wave-per-node blocks
  int ngb = (NODES / 16 + 3) / 4;           // gemm blocks (4 waves x 16 rows)

  // layer 0
  k_gemm_mfma<16, 4><<<ngb, 256, 0, stream>>>(xb0, Bp0, hb, as0, ad0, als, ald, NODES, 256, 128);
  k_agg4<<<nwb, 256, 0, stream>>>(hb, als, ald, offs, ssrc, b0, xb1);

  // layer 1
  k_gemm_mfma<16, 4><<<ngb, 256, 0, stream>>>(xb1, Bp1, hb, as1, ad1, als, ald, NODES, 256, 256);
  k_agg4<<<nwb, 256, 0, stream>>>(hb, als, ald, offs, ssrc, b1, xb2);

  // layer 2
  k_gemm_mfma<3, 1><<<ngb, 256, 0, stream>>>(xb2, Bp2, hb, as2, ad2, als, ald, NODES, 40, 256);
  k_agg1<<<nwb, 256, 0, stream>>>(hb, als, ald, offs, ssrc, b2, out);
}

// Round 5
// 337.152 us; speedup vs baseline: 2.2812x; 1.2266x over previous
//
#include <hip/hip_runtime.h>
#include <math.h>

#define NODES 50000
#define NEDGES 800000
#define TOT_E (NEDGES + NODES)
#define SCAN_B 256
#define SCAN_NB ((NODES + SCAN_B - 1) / SCAN_B)

typedef __attribute__((ext_vector_type(8))) short short8v;
typedef __attribute__((ext_vector_type(4))) float f32x4;

static __device__ __forceinline__ float lrelu(float z) {
  return z > 0.f ? z : 0.2f * z;
}
static __device__ __forceinline__ float b2f(ushort u) {
  union { uint i; float f; } v; v.i = ((uint)u) << 16; return v.f;
}
static __device__ __forceinline__ ushort f2b(float f) {
  union { float f; uint i; } v; v.f = f;
  uint r = v.i + 0x7fff + ((v.i >> 16) & 1);
  return (ushort)(r >> 16);
}

// ---------------- CSR build ----------------
__global__ void k_hist(const int* __restrict__ dst, int* __restrict__ counts) {
  int stride = gridDim.x * blockDim.x;
  for (int i = blockIdx.x * blockDim.x + threadIdx.x; i < TOT_E; i += stride) {
    int d = (i < NEDGES) ? dst[i] : (i - NEDGES);
    atomicAdd(&counts[d], 1);
  }
}

__global__ __launch_bounds__(SCAN_B) void k_scan_red(const int* __restrict__ counts,
                                                     int* __restrict__ bsum) {
  __shared__ int sm[SCAN_B];
  int idx = blockIdx.x * SCAN_B + threadIdx.x;
  int v = (idx < NODES) ? counts[idx] : 0;
  sm[threadIdx.x] = v;
  __syncthreads();
  for (int off = SCAN_B / 2; off > 0; off >>= 1) {
    if (threadIdx.x < off) sm[threadIdx.x] += sm[threadIdx.x + off];
    __syncthreads();
  }
  if (threadIdx.x == 0) bsum[blockIdx.x] = sm[0];
}

__global__ __launch_bounds__(256) void k_scan_part(const int* __restrict__ bsum,
                                                   int* __restrict__ bpre) {
  __shared__ int sm[256];
  int tid = threadIdx.x;
  int v = (tid < SCAN_NB) ? bsum[tid] : 0;
  sm[tid] = v;
  __syncthreads();
  for (int off = 1; off < 256; off <<= 1) {
    int t = (tid >= off) ? sm[tid - off] : 0;
    __syncthreads();
    sm[tid] += t;
    __syncthreads();
  }
  if (tid < SCAN_NB) bpre[tid] = sm[tid] - v;  // exclusive
}

__global__ __launch_bounds__(SCAN_B) void k_scan_emit(const int* __restrict__ counts,
    const int* __restrict__ bpre, int* __restrict__ offs, int* __restrict__ cur) {
  __shared__ int sm[SCAN_B];
  int idx = blockIdx.x * SCAN_B + threadIdx.x;
  int tid = threadIdx.x;
  int v = (idx < NODES) ? counts[idx] : 0;
  sm[tid] = v;
  __syncthreads();
  for (int off = 1; off < SCAN_B; off <<= 1) {
    int t = (tid >= off) ? sm[tid - off] : 0;
    __syncthreads();
    sm[tid] += t;
    __syncthreads();
  }
  int base = bpre[blockIdx.x];
  int excl = base + sm[tid] - v;
  if (idx < NODES) { offs[idx] = excl; cur[idx] = excl; }
  if (idx == NODES - 1) offs[NODES] = excl + v;
}

__global__ void k_scatter(const int* __restrict__ src, const int* __restrict__ dst,
                          int* __restrict__ cur, int* __restrict__ ssrc) {
  int stride = gridDim.x * blockDim.x;
  for (int i = blockIdx.x * blockDim.x + threadIdx.x; i < TOT_E; i += stride) {
    int s, d;
    if (i < NEDGES) { s = src[i]; d = dst[i]; } else { s = i - NEDGES; d = s; }
    int pos = atomicAdd(&cur[d], 1);
    ssrc[pos] = s;
  }
}

// ---------------- casts / packing ----------------
__global__ void k_cast4(const float* __restrict__ X, ushort* __restrict__ Xb, int total4) {
  int stride = gridDim.x * blockDim.x;
  for (int i = blockIdx.x * blockDim.x + threadIdx.x; i < total4; i += stride) {
    float4 v = *(const float4*)&X[i * 4];
    ushort4 o;
    o.x = f2b(v.x); o.y = f2b(v.y); o.z = f2b(v.z); o.w = f2b(v.w);
    *(ushort4*)&Xb[i * 4] = o;
  }
}

// Bpack[kf][nf][lane][8] = B[kf*32 + (lane>>4)*8 + i][nf*16 + (lane&15)]
__global__ void k_packB(const float* __restrict__ W, ushort* __restrict__ Bp,
                        int N, int NF, int total) {
  int idx = blockIdx.x * blockDim.x + threadIdx.x;
  if (idx >= total) return;
  int i = idx & 7;
  int lane = (idx >> 3) & 63;
  int rem = idx >> 9;
  int nf = rem % NF;
  int kf = rem / NF;
  int k = kf * 32 + (lane >> 4) * 8 + i;
  int col = nf * 16 + (lane & 15);
  float v = (col < N) ? W[(size_t)k * N + col] : 0.f;
  Bp[idx] = f2b(v);
}

// ---------------- register-resident-B MFMA GEMM + fused logits ----------------
// Each wave owns a 64-col group (cg) with its B-panel entirely in VGPRs,
// and grid-strides over 16-row M-strips. For HEADS=4 a col-group == one head,
// so the fused logit reduction needs no cross-wave communication.
template<int KF, int NFW, int CG, int HEADS, int NF_TOT>
__global__ __launch_bounds__(256, 2) void k_gemm_reg(
    const ushort* __restrict__ A, const ushort* __restrict__ Bp,
    ushort* __restrict__ H, const float* __restrict__ a_s, const float* __restrict__ a_d,
    float* __restrict__ al_s, float* __restrict__ al_d, int M, int N, int K) {
  int wave = (blockIdx.x * blockDim.x + threadIdx.x) >> 6;
  int lane = threadIdx.x & 63;
  int lg = lane >> 4;
  int lr = lane & 15;
  int total_waves = (gridDim.x * blockDim.x) >> 6;
  int wpc = total_waves / CG;
  int cg = wave / wpc;
  int mslot = wave - cg * wpc;
  if (cg >= CG) return;

  // B panel -> registers (shared across all strips; L2-broadcast loads)
  short8v b[KF][NFW];
#pragma unroll
  for (int kf = 0; kf < KF; ++kf)
#pragma unroll
    for (int n = 0; n < NFW; ++n)
      b[kf][n] = *(const short8v*)(Bp + ((size_t)(kf * NF_TOT + cg * NFW + n) * 64 + lane) * 8);

  float asc[NFW], adc[NFW];
#pragma unroll
  for (int n = 0; n < NFW; ++n) {
    int col = (cg * NFW + n) * 16 + lr;
    bool ok = col < N;
    asc[n] = ok ? a_s[col] : 0.f;
    adc[n] = ok ? a_d[col] : 0.f;
  }

  int nstrips = M >> 4;
  for (int strip = mslot; strip < nstrips; strip += wpc) {
    const ushort* arow = A + (size_t)(strip * 16 + lr) * K + lg * 8;
    short8v a[KF];
#pragma unroll
    for (int kf = 0; kf < KF; ++kf) a[kf] = *(const short8v*)(arow + kf * 32);
    f32x4 acc[NFW];
#pragma unroll
    for (int n = 0; n < NFW; ++n) acc[n] = (f32x4){0.f, 0.f, 0.f, 0.f};
#pragma unroll
    for (int kf = 0; kf < KF; ++kf)
#pragma unroll
      for (int n = 0; n < NFW; ++n)
        acc[n] = __builtin_amdgcn_mfma_f32_16x16x32_bf16(a[kf], b[kf][n], acc[n], 0, 0, 0);

    // H write: col = (cg*NFW+n)*16 + lr, row = strip*16 + lg*4 + r
#pragma unroll
    for (int n = 0; n < NFW; ++n) {
      int col = (cg * NFW + n) * 16 + lr;
      if (col < N) {
#pragma unroll
        for (int r = 0; r < 4; ++r) {
          int row = strip * 16 + lg * 4 + r;
          H[(size_t)row * N + col] = f2b(acc[n][r]);
        }
      }
    }

    // fused attention logits for this wave's head
    float ps[4], pd[4];
#pragma unroll
    for (int r = 0; r < 4; ++r) {
      float s = 0.f, d = 0.f;
#pragma unroll
      for (int n = 0; n < NFW; ++n) {
        s += acc[n][r] * asc[n];
        d += acc[n][r] * adc[n];
      }
      ps[r] = s; pd[r] = d;
    }
#pragma unroll
    for (int off = 1; off <= 8; off <<= 1)
#pragma unroll
      for (int t = 0; t < 4; ++t) {
        ps[t] += __shfl_xor(ps[t], off);
        pd[t] += __shfl_xor(pd[t], off);
      }
    if (lr < 4) {
      int row = strip * 16 + lg * 4 + lr;
      if (HEADS == 4) {
        al_s[row * 4 + cg] = ps[lr];
        al_d[row * 4 + cg] = pd[lr];
      } else {
        al_s[row] = ps[lr];
        al_d[row] = pd[lr];
      }
    }
  }
}

// ---------------- aggregation: wave per dst node ----------------
// layers 0/1: H=4, C=64; phase2 2 edges/iter, manually unrolled x2
__global__ __launch_bounds__(256) void k_agg4(const ushort* __restrict__ hb,
    const float* __restrict__ al_s, const float* __restrict__ al_d,
    const int* __restrict__ offs, const int* __restrict__ ssrc,
    const float* __restrict__ bias, ushort* __restrict__ outb) {
  int wid = (blockIdx.x * blockDim.x + threadIdx.x) >> 6;
  if (wid >= NODES) return;
  int lane = threadIdx.x & 63;
  int beg = offs[wid], end = offs[wid + 1];
  int h1 = lane >> 4;
  int es = lane & 15;
  float ald = al_d[wid * 4 + h1];

  float m = -1e30f, s = 0.f;
  for (int i = beg + es; i < end; i += 16) {
    int sv = ssrc[i];
    float z = lrelu(al_s[sv * 4 + h1] + ald);
    if (z > m) { s = s * __expf(m - z) + 1.f; m = z; }
    else s += __expf(z - m);
  }
#pragma unroll
  for (int off = 1; off <= 8; off <<= 1) {
    float mo = __shfl_xor(m, off), so = __shfl_xor(s, off);
    float mn = fmaxf(m, mo);
    s = s * __expf(m - mn) + so * __expf(mo - mn);
    m = mn;
  }
  float inv = 1.f / s;

  int half = lane >> 5;
  int cl = lane & 31;
  int hh = cl >> 3;
  int srcl = hh * 16;
  float mh = __shfl(m, srcl);
  float invh = __shfl(inv, srcl);
  float aldh = __shfl(ald, srcl);
  float acc[8] = {0.f, 0.f, 0.f, 0.f, 0.f, 0.f, 0.f, 0.f};
  int i = beg + half;
  for (; i + 2 < end; i += 4) {
    int sv0 = ssrc[i], sv1 = ssrc[i + 2];
    float z0 = lrelu(al_s[sv0 * 4 + hh] + aldh);
    float z1 = lrelu(al_s[sv1 * 4 + hh] + aldh);
    float a0 = __expf(z0 - mh) * invh;
    float a1 = __expf(z1 - mh) * invh;
    short8v hv0 = *(const short8v*)(hb + (size_t)sv0 * 256 + cl * 8);
    short8v hv1 = *(const short8v*)(hb + (size_t)sv1 * 256 + cl * 8);
#pragma unroll
    for (int j = 0; j < 8; ++j) acc[j] += a0 * b2f((ushort)hv0[j]);
#pragma unroll
    for (int j = 0; j < 8; ++j) acc[j] += a1 * b2f((ushort)hv1[j]);
  }
  for (; i < end; i += 2) {
    int sv = ssrc[i];
    float z = lrelu(al_s[sv * 4 + hh] + aldh);
    float alpha = __expf(z - mh) * invh;
    short8v hv = *(const short8v*)(hb + (size_t)sv * 256 + cl * 8);
#pragma unroll
    for (int j = 0; j < 8; ++j) acc[j] += alpha * b2f((ushort)hv[j]);
  }
#pragma unroll
  for (int j = 0; j < 8; ++j) acc[j] += __shfl_xor(acc[j], 32);
  if (half == 0) {
    short8v o;
#pragma unroll
    for (int j = 0; j < 8; ++j) {
      float v = acc[j] + bias[cl * 8 + j];
      o[j] = (short)f2b(v > 0.f ? v : __expf(v) - 1.f);
    }
    *(short8v*)(outb + (size_t)wid * 256 + cl * 8) = o;
  }
}

// layer 2: H=1, C=40; phase2 4 edges/iter, unrolled x2
__global__ __launch_bounds__(256) void k_agg1(const ushort* __restrict__ hb,
    const float* __restrict__ al_s, const float* __restrict__ al_d,
    const int* __restrict__ offs, const int* __restrict__ ssrc,
    const float* __restrict__ bias, float* __restrict__ out) {
  int wid = (blockIdx.x * blockDim.x + threadIdx.x) >> 6;
  if (wid >= NODES) return;
  int lane = threadIdx.x & 63;
  int beg = offs[wid], end = offs[wid + 1];
  float ald = al_d[wid];

  float m = -1e30f, s = 0.f;
  for (int i = beg + lane; i < end; i += 64) {
    float z = lrelu(al_s[ssrc[i]] + ald);
    if (z > m) { s = s * __expf(m - z) + 1.f; m = z; }
    else s += __expf(z - m);
  }
#pragma unroll
  for (int off = 1; off <= 32; off <<= 1) {
    float mo = __shfl_xor(m, off), so = __shfl_xor(s, off);
    float mn = fmaxf(m, mo);
    s = s * __expf(m - mn) + so * __expf(mo - mn);
    m = mn;
  }
  float inv = 1.f / s;

  int e = lane >> 4;
  int q = lane & 15;
  bool act = q < 10;
  float acc[4] = {0.f, 0.f, 0.f, 0.f};
  int i = beg + e;
  for (; i + 4 < end; i += 8) {
    int sv0 = ssrc[i], sv1 = ssrc[i + 4];
    float z0 = lrelu(al_s[sv0] + ald);
    float z1 = lrelu(al_s[sv1] + ald);
    float a0 = __expf(z0 - m) * inv;
    float a1 = __expf(z1 - m) * inv;
    if (act) {
      ushort4 hv0 = *(const ushort4*)&hb[(size_t)sv0 * 40 + q * 4];
      ushort4 hv1 = *(const ushort4*)&hb[(size_t)sv1 * 40 + q * 4];
      acc[0] += a0 * b2f(hv0.x) + a1 * b2f(hv1.x);
      acc[1] += a0 * b2f(hv0.y) + a1 * b2f(hv1.y);
      acc[2] += a0 * b2f(hv0.z) + a1 * b2f(hv1.z);
      acc[3] += a0 * b2f(hv0.w) + a1 * b2f(hv1.w);
    }
  }
  for (; i < end; i += 4) {
    int sv = ssrc[i];
    float z = lrelu(al_s[sv] + ald);
    float alpha = __expf(z - m) * inv;
    if (act) {
      ushort4 hv = *(const ushort4*)&hb[(size_t)sv * 40 + q * 4];
      acc[0] += alpha * b2f(hv.x); acc[1] += alpha * b2f(hv.y);
      acc[2] += alpha * b2f(hv.z); acc[3] += alpha * b2f(hv.w);
    }
  }
#pragma unroll
  for (int j = 0; j < 4; ++j) {
    acc[j] += __shfl_xor(acc[j], 16);
    acc[j] += __shfl_xor(acc[j], 32);
  }
  float v[4];
  float mm = -1e30f;
  if (act) {
#pragma unroll
    for (int j = 0; j < 4; ++j) {
      v[j] = acc[j] + bias[q * 4 + j];
      mm = fmaxf(mm, v[j]);
    }
  }
#pragma unroll
  for (int off = 1; off <= 8; off <<= 1) mm = fmaxf(mm, __shfl_xor(mm, off));
  float se = 0.f;
  if (act) {
#pragma unroll
    for (int j = 0; j < 4; ++j) se += __expf(v[j] - mm);
  }
#pragma unroll
  for (int off = 1; off <= 8; off <<= 1) se += __shfl_xor(se, off);
  if (act && e == 0) {
    float lse = mm + __logf(se);
    float4 o;
    o.x = v[0] - lse; o.y = v[1] - lse; o.z = v[2] - lse; o.w = v[3] - lse;
    *(float4*)&out[(size_t)wid * 40 + q * 4] = o;
  }
}

// ---------------- launch ----------------
extern "C" void kernel_launch(void* const* d_in, const int* in_sizes, int n_in,
                              void* d_out, int out_size, void* d_ws, size_t ws_size,
                              hipStream_t stream) {
  const float* x   = (const float*)d_in[0];
  const int*   ei  = (const int*)d_in[1];
  const float* W0  = (const float*)d_in[2];
  const float* as0 = (const float*)d_in[3];
  const float* ad0 = (const float*)d_in[4];
  const float* b0  = (const float*)d_in[5];
  const float* W1  = (const float*)d_in[6];
  const float* as1 = (const float*)d_in[7];
  const float* ad1 = (const float*)d_in[8];
  const float* b1  = (const float*)d_in[9];
  const float* W2  = (const float*)d_in[10];
  const float* as2 = (const float*)d_in[11];
  const float* ad2 = (const float*)d_in[12];
  const float* b2  = (const float*)d_in[13];
  float* out = (float*)d_out;

  char* p = (char*)d_ws;
  auto take = [&](size_t bytes) {
    char* q = p;
    p += (bytes + 255) & ~(size_t)255;
    return (void*)q;
  };
  ushort* xb0 = (ushort*)take((size_t)NODES * 128 * 2);
  ushort* xb1 = (ushort*)take((size_t)NODES * 256 * 2);
  ushort* xb2 = (ushort*)take((size_t)NODES * 256 * 2);
  ushort* hb  = (ushort*)take((size_t)NODES * 256 * 2);
  float* als  = (float*)take((size_t)NODES * 4 * 4);
  float* ald  = (float*)take((size_t)NODES * 4 * 4);
  int* ssrc   = (int*)take((size_t)TOT_E * 4);
  int* offs   = (int*)take((size_t)(NODES + 1) * 4);
  int* cur    = (int*)take((size_t)NODES * 4);
  int* cnt    = (int*)take((size_t)NODES * 4);
  int* bsum   = (int*)take((size_t)SCAN_NB * 4);
  int* bpre   = (int*)take((size_t)SCAN_NB * 4);
  ushort* Bp0 = (ushort*)take((size_t)4 * 16 * 512 * 2);
  ushort* Bp1 = (ushort*)take((size_t)8 * 16 * 512 * 2);
  ushort* Bp2 = (ushort*)take((size_t)8 * 3 * 512 * 2);

  // CSR build (dst-sorted edge list incl. self-loops)
  hipMemsetAsync(cnt, 0, (size_t)NODES * 4, stream);
  k_hist<<<2048, 256, 0, stream>>>(ei + NEDGES, cnt);
  k_scan_red<<<SCAN_NB, SCAN_B, 0, stream>>>(cnt, bsum);
  k_scan_part<<<1, 256, 0, stream>>>(bsum, bpre);
  k_scan_emit<<<SCAN_NB, SCAN_B, 0, stream>>>(cnt, bpre, offs, cur);
  k_scatter<<<2048, 256, 0, stream>>>(ei, ei + NEDGES, cur, ssrc);

  // bf16 casts / weight packs
  k_cast4<<<2048, 256, 0, stream>>>(x, xb0, NODES * 128 / 4);
  {
    int t0 = 4 * 16 * 512;  k_packB<<<(t0 + 255) / 256, 256, 0, stream>>>(W0, Bp0, 256, 16, t0);
    int t1 = 8 * 16 * 512;  k_packB<<<(t1 + 255) / 256, 256, 0, stream>>>(W1, Bp1, 256, 16, t1);
    int t2 = 8 * 3 * 512;   k_packB<<<(t2 + 255) / 256, 256, 0, stream>>>(W2, Bp2, 40, 3, t2);
  }

  int nwb = (NODES * 64 + 255) / 256;       // wave-per-node blocks
  int ggb = 512;                            // gemm grid: 2048 waves

  // layer 0
  k_gemm_reg<4, 4, 4, 4, 16><<<ggb, 256, 0, stream>>>(xb0, Bp0, hb, as0, ad0, als, ald, NODES, 256, 128);
  k_agg4<<<nwb, 256, 0, stream>>>(hb, als, ald, offs, ssrc, b0, xb1);

  // layer 1
  k_gemm_reg<8, 4, 4, 4, 16><<<ggb, 256, 0, stream>>>(xb1, Bp1, hb, as1, ad1, als, ald, NODES, 256, 256);
  k_agg4<<<nwb, 256, 0, stream>>>(hb, als, ald, offs, ssrc, b1, xb2);

  // layer 2
  k_gemm_reg<8, 3, 1, 1, 3><<<ggb, 256, 0, stream>>>(xb2, Bp2, hb, as2, ad2, als, ald, NODES, 40, 256);
  k_agg1<<<nwb, 256, 0, stream>>>(hb, als, ald, offs, ssrc, b2, out);
}